// Round 3
// baseline (149.647 us; speedup 1.0000x reference)
//
#include <hip/hip_runtime.h>
#include <hip/hip_bf16.h>

#define NG 128
#define KTOP 4
#define THREADS 256
#define WAVES (THREADS / 64)

// lexicographic "better": higher IoU wins; exact fp32 tie -> lower index wins
// (matches jax.lax.top_k / stable descending argsort tie-breaking)
__device__ __forceinline__ bool better(float va, int ia, float vb, int ib) {
    return (va > vb) || (va == vb && ia < ib);
}

__global__ __launch_bounds__(THREADS)
void ptl_topk_encode_kernel(const float* __restrict__ rois,    // (B,2,P,4) f32
                            const float* __restrict__ targets, // (B,G,4)  f32
                            float* __restrict__ out,           // (B, G*K, 4) f32
                            int P, int nblocks)
{
    #pragma clang fp contract(off)

    const int bg = blockIdx.x;              // b * NG + g
    if (bg >= nblocks) return;
    const int b  = bg >> 7;                 // NG = 128
    const int g  = bg & (NG - 1);

    // defaults = rpn_rois[:, 1]
    const float* priors = rois + ((size_t)(2 * b + 1)) * (size_t)P * 4u;
    const float* t      = targets + ((size_t)(b * NG + g)) * 4u;

    const float t0 = t[0], t1 = t[1], t2 = t[2], t3 = t[3];
    const float area_t = (t2 - t0) * (t3 - t1);

    // ---- phase 1: per-thread top-4, sorted descending (index asc on ties) ----
    float v0 = -1.f, v1 = -1.f, v2 = -1.f, v3 = -1.f;
    int   j0 = 0,    j1 = 0,    j2 = 0,    j3 = 0;   // safe sentinels

    const float4* pv = (const float4*)priors;   // one box per float4, 16B aligned
    for (int i = threadIdx.x; i < P; i += THREADS) {
        float4 q = pv[i];
        float p0 = q.x, p1 = q.y, p2 = q.z, p3 = q.w;

        // IoU, bit-exact vs numpy fp32 (no contraction, IEEE div, same op order)
        float ltx = fmaxf(t0, p0), lty = fmaxf(t1, p1);
        float rbx = fminf(t2, p2), rby = fminf(t3, p3);
        float wx = fmaxf(rbx - ltx, 0.0f);
        float wy = fmaxf(rby - lty, 0.0f);
        float inter  = wx * wy;
        float area_p = (p2 - p0) * (p3 - p1);
        float iou = inter / ((area_t + area_p) - inter);

        // strict > keeps earlier (lower) index on ties; i increases monotonically
        if (iou > v3) {
            if (iou > v1) {
                if (iou > v0) { v3=v2;j3=j2; v2=v1;j2=j1; v1=v0;j1=j0; v0=iou;j0=i; }
                else          { v3=v2;j3=j2; v2=v1;j2=j1; v1=iou;j1=i; }
            } else {
                if (iou > v2) { v3=v2;j3=j2; v2=iou;j2=i; }
                else          { v3=iou;j3=i; }
            }
        }
    }

    // ---- phase 2: tournament — 4 rounds of block-wide argmax ----
    __shared__ float bw_v[WAVES];
    __shared__ int   bw_i[WAVES];
    __shared__ int   bw_t[WAVES];
    __shared__ int   win_tid;

    const int lane = threadIdx.x & 63;
    const int wv   = threadIdx.x >> 6;

    const float gcx = (t0 + t2) * 0.5f;
    const float gcy = (t1 + t3) * 0.5f;
    const float gw  = t2 - t0;
    const float gh  = t3 - t1;

    int p = 0;   // how many of my entries have been consumed globally

    for (int k = 0; k < KTOP; ++k) {
        // my current best unconsumed candidate (compile-time-indexed selects)
        float cv; int ci;
        if      (p == 0) { cv = v0; ci = j0; }
        else if (p == 1) { cv = v1; ci = j1; }
        else if (p == 2) { cv = v2; ci = j2; }
        else if (p == 3) { cv = v3; ci = j3; }
        else             { cv = -2.f; ci = 0; }
        int ct = threadIdx.x;

        // wave-level argmax (distinct (v,i) per thread -> unique winner)
        #pragma unroll
        for (int d = 32; d >= 1; d >>= 1) {
            float ov = __shfl_down(cv, d, 64);
            int   oi = __shfl_down(ci, d, 64);
            int   ot = __shfl_down(ct, d, 64);
            if (better(ov, oi, cv, ci)) { cv = ov; ci = oi; ct = ot; }
        }
        if (lane == 0) { bw_v[wv] = cv; bw_i[wv] = ci; bw_t[wv] = ct; }
        __syncthreads();

        if (threadIdx.x == 0) {
            float bv = bw_v[0]; int bi = bw_i[0]; int bt = bw_t[0];
            #pragma unroll
            for (int w = 1; w < WAVES; ++w)
                if (better(bw_v[w], bw_i[w], bv, bi)) { bv = bw_v[w]; bi = bw_i[w]; bt = bw_t[w]; }
            win_tid = bt;
        }
        __syncthreads();

        if (threadIdx.x == win_tid) {
            // my candidate (at position p) won round k: encode + store
            int bi;
            if      (p == 0) bi = j0;
            else if (p == 1) bi = j1;
            else if (p == 2) bi = j2;
            else             bi = j3;
            bi = min(max(bi, 0), P - 1);   // defensive clamp

            float4 q = pv[bi];
            float pcx = (q.x + q.z) * 0.5f;
            float pcy = (q.y + q.w) * 0.5f;
            float pw  = q.z - q.x;
            float ph  = q.w - q.y;
            float ox = (gcx - pcx) / (0.1f * pw);
            float oy = (gcy - pcy) / (0.1f * ph);
            float ow = logf(gw / pw) / 0.2f;
            float oh = logf(gh / ph) / 0.2f;

            size_t o = ((size_t)bg * KTOP + k) * 4;
            out[o + 0] = ox;
            out[o + 1] = oy;
            out[o + 2] = ow;
            out[o + 3] = oh;

            ++p;   // consume my entry
        }
        __syncthreads();
    }
}

extern "C" void kernel_launch(void* const* d_in, const int* in_sizes, int n_in,
                              void* d_out, int out_size, void* d_ws, size_t ws_size,
                              hipStream_t stream) {
    const float* rois    = (const float*)d_in[0];
    const float* targets = (const float*)d_in[1];
    float* out = (float*)d_out;

    const int B = in_sizes[1] / (NG * 4);          // 16
    const int P = in_sizes[0] / (B * 2 * 4);       // 32768
    const int nblocks = B * NG;                    // 2048

    ptl_topk_encode_kernel<<<dim3(nblocks), dim3(THREADS), 0, stream>>>(
        rois, targets, out, P, nblocks);
}